// Round 10
// baseline (1069.552 us; speedup 1.0000x reference)
//
#include <hip/hip_runtime.h>
#include <math.h>

// ---------- types & helpers ----------
typedef __attribute__((ext_vector_type(4))) float f32x4;
typedef __attribute__((ext_vector_type(8))) short bf16x8;

__device__ __forceinline__ short f2bf(float f) {
  unsigned u = __builtin_bit_cast(unsigned, f);
  u += 0x7FFFu + ((u >> 16) & 1u);          // RNE
  return (short)(u >> 16);
}
__device__ __forceinline__ float bf2f(short s) {
  unsigned u = ((unsigned)(unsigned short)s) << 16;
  return __builtin_bit_cast(float, u);
}

#define MFMA(A, B, C) __builtin_amdgcn_mfma_f32_16x16x32_bf16((A), (B), (C), 0, 0, 0)

// async global->LDS, 16B per lane; LDS dst is wave-uniform base + lane*16
#define GLOAD16(gsrc, ldst)                                                      \
  __builtin_amdgcn_global_load_lds(                                              \
      (const __attribute__((address_space(1))) void*)(gsrc),                     \
      (__attribute__((address_space(3))) void*)(ldst), 16, 0, 0)

#define LOG100 4.605170185988092f

// ---------- convert: x -> bf16, weights -> transposed bf16 ----------
__global__ __launch_bounds__(256) void convert_kernel(
    const float* __restrict__ x,
    const float* __restrict__ qw0, const float* __restrict__ qw1,
    const float* __restrict__ pw0, const float* __restrict__ pw1,
    const float* __restrict__ w1, const float* __restrict__ w2,
    short* __restrict__ xb,
    short* __restrict__ qwT0, short* __restrict__ qwT1,
    short* __restrict__ pwT0, short* __restrict__ pwT1,
    short* __restrict__ w1T, short* __restrict__ w2T) {
  int bid = blockIdx.x;
  int tid = threadIdx.x;
  if (bid < 8192) {  // x: 16777216 elements, 8 per thread
    int base = (bid * 256 + tid) * 8;
    bf16x8 o;
#pragma unroll
    for (int j = 0; j < 8; ++j) o[j] = f2bf(x[base + j]);
    *(bf16x8*)&xb[base] = o;
    return;
  }
  int idx = (bid - 8192) * 256 + tid;  // 0..1048575 over weights
  if (idx < 196608) { int n = idx >> 8, k = idx & 255; qwT0[idx] = f2bf(qw0[k * 768 + n]); return; }
  idx -= 196608;
  if (idx < 196608) { int n = idx >> 8, k = idx & 255; qwT1[idx] = f2bf(qw1[k * 768 + n]); return; }
  idx -= 196608;
  if (idx < 65536) { int n = idx >> 8, k = idx & 255; pwT0[idx] = f2bf(pw0[k * 256 + n]); return; }
  idx -= 65536;
  if (idx < 65536) { int n = idx >> 8, k = idx & 255; pwT1[idx] = f2bf(pw1[k * 256 + n]); return; }
  idx -= 65536;
  if (idx < 262144) { int n = idx >> 8, k = idx & 255; w1T[idx] = f2bf(w1[k * 1024 + n]); return; }
  idx -= 262144;
  { int n = idx >> 10, k = idx & 1023; w2T[idx] = f2bf(w2[k * 256 + n]); }
}

// ---------- qkv GEMM: 8-wave BM=128 (2 windows), BN=256, gload_lds staging ----------
// grid (nmb/2, 3), 512 threads. Window gather folded into per-lane global src addr.
template <bool SHIFTED>
__global__ __launch_bounds__(512) void qkv_kernel(
    const short* __restrict__ xb, const short* __restrict__ wT,
    const float* __restrict__ bias,
    short* __restrict__ Q, short* __restrict__ K, short* __restrict__ V,
    int mblk_base) {
  __shared__ short A[128 * 64];   // 16 KB, row r at A[r*64]
  __shared__ short Bs[256 * 64];  // 32 KB, col c at Bs[c*64]
  const int mloc = blockIdx.x;          // window-pair within chunk
  const int which = blockIdx.y;
  const int tid = threadIdx.x;
  const int lane = tid & 63, wid = tid >> 6;
  const int wr = wid >> 2, wc = wid & 3;
  const int l15 = lane & 15, lg = lane >> 4;
  const int lrow = lane >> 3, lcol8 = (lane & 7) * 8;

  // per-lane gathered token for the lane's two staged rows (it=0,1)
  int tokA[2];
#pragma unroll
  for (int it = 0; it < 2; ++it) {
    int r = wid * 16 + it * 8 + lrow;          // block-row 0..127
    int mg = mblk_base + mloc * 2 + (r >> 6);  // global window id
    int b = mg >> 6, wi = mg & 63;
    int hs = ((wi >> 3) << 3) + ((r >> 3) & 7);
    int ws2 = ((wi & 7) << 3) + (r & 7);
    if (SHIFTED) { hs = (hs + 4) & 63; ws2 = (ws2 + 4) & 63; }
    tokA[it] = b * 4096 + hs * 64 + ws2;
  }

  f32x4 zf = {0.f, 0.f, 0.f, 0.f};
  f32x4 acc[4][4];
#pragma unroll
  for (int i = 0; i < 4; ++i)
#pragma unroll
    for (int j = 0; j < 4; ++j) acc[i][j] = zf;

#pragma unroll 1
  for (int kc = 0; kc < 4; ++kc) {
    __syncthreads();
#pragma unroll
    for (int it = 0; it < 2; ++it) {
      int r0 = wid * 16 + it * 8;
      GLOAD16(&xb[(size_t)tokA[it] * 256 + kc * 64 + lcol8], &A[r0 * 64]);
    }
#pragma unroll
    for (int it = 0; it < 4; ++it) {
      int c0 = wid * 32 + it * 8;
      GLOAD16(&wT[(size_t)(which * 256 + c0 + lrow) * 256 + kc * 64 + lcol8], &Bs[c0 * 64]);
    }
    __syncthreads();
#pragma unroll
    for (int ks = 0; ks < 2; ++ks) {
      bf16x8 af[4], bfr[4];
#pragma unroll
      for (int ti = 0; ti < 4; ++ti)
        af[ti] = *(bf16x8*)&A[(wr * 64 + ti * 16 + l15) * 64 + ks * 32 + lg * 8];
#pragma unroll
      for (int tj = 0; tj < 4; ++tj)
        bfr[tj] = *(bf16x8*)&Bs[(wc * 64 + tj * 16 + l15) * 64 + ks * 32 + lg * 8];
#pragma unroll
      for (int ti = 0; ti < 4; ++ti)
#pragma unroll
        for (int tj = 0; tj < 4; ++tj) acc[ti][tj] = MFMA(af[ti], bfr[tj], acc[ti][tj]);
    }
  }
  // epilogue: +bias, write bf16 window layout (V transposed). wave's window = mloc*2+wr.
  short* outp = (which == 0) ? Q : (which == 1) ? K : V;
  const int lw = mloc * 2 + wr;   // chunk-local window
#pragma unroll
  for (int tj = 0; tj < 4; ++tj) {
    int c = wc * 64 + tj * 16 + l15;      // 0..255 within Q|K|V
    int h = c >> 5, d = c & 31;
    float bv = bias[which * 256 + c];
    int hb = (lw * 8 + h) * 2048;
#pragma unroll
    for (int ti = 0; ti < 4; ++ti) {
#pragma unroll
      for (int idx = 0; idx < 4; ++idx) {
        int n = ti * 16 + lg * 4 + idx;   // token within window
        float v = acc[ti][tj][idx] + bv;
        int off = hb + (which == 2 ? (d * 64 + n) : (n * 32 + d));
        outp[off] = f2bf(v);
      }
    }
  }
}

// ---------- fused attention + proj + LN + residual ----------
// Head loop fully unrolled (ILP across the two serial head chains); setprio around MFMAs.
template <bool SHIFTED>
__global__ __launch_bounds__(256, 2) void attn_kernel(
    const short* __restrict__ Q, const short* __restrict__ K, const short* __restrict__ V,
    const float* __restrict__ logit_scale,
    const short* __restrict__ projT, const float* __restrict__ proj_b,
    const float* __restrict__ ln_w, const float* __restrict__ ln_b,
    const float* x_old, float* x_new, short* x_new_bf,
    int mblk_base) {
  __shared__ short Plds[4][64][72];
  __shared__ short Olds[64][264];
  __shared__ float red1[4][64], red2[4][64];
  __shared__ int ids[64];

  const int mloc = blockIdx.x;
  const int mg = mblk_base + mloc;
  const int b = mg >> 6, wi = mg & 63;
  const int h0 = (wi >> 3) << 3, w0c = (wi & 7) << 3;
  const int tid = threadIdx.x;
  const int lane = tid & 63, wid = tid >> 6;
  const int l15 = lane & 15, lg = lane >> 4;

  if (SHIFTED) {
    if (tid < 64) {
      int hs = h0 + (tid >> 3), ws2 = w0c + (tid & 7);
      int rr = (hs < 56) ? 0 : ((hs < 60) ? 1 : 2);
      int rc = (ws2 < 56) ? 0 : ((ws2 < 60) ? 1 : 2);
      ids[tid] = rr * 3 + rc;
    }
    __syncthreads();
  }

  f32x4 zf = {0.f, 0.f, 0.f, 0.f};

#pragma unroll
  for (int hp = 0; hp < 2; ++hp) {
    const int h = wid * 2 + hp;
    const short* Qh = Q + (mloc * 8 + h) * 2048;
    const short* Kh = K + (mloc * 8 + h) * 2048;
    const short* Vt = V + (mloc * 8 + h) * 2048;
    const float sc = __expf(fminf(logit_scale[h], LOG100));

    bf16x8 qf[4];
#pragma unroll
    for (int ti = 0; ti < 4; ++ti) {
      qf[ti] = *(const bf16x8*)&Qh[(ti * 16 + l15) * 32 + lg * 8];
      float ss = 0.f;
#pragma unroll
      for (int j = 0; j < 8; ++j) { float q = bf2f(qf[ti][j]); ss += q * q; }
      ss += __shfl_xor(ss, 16); ss += __shfl_xor(ss, 32);
      float f = sc / fmaxf(sqrtf(ss), 1e-6f);
#pragma unroll
      for (int j = 0; j < 8; ++j) qf[ti][j] = f2bf(bf2f(qf[ti][j]) * f);
    }
    bf16x8 kf[4];
#pragma unroll
    for (int tj = 0; tj < 4; ++tj) {
      kf[tj] = *(const bf16x8*)&Kh[(tj * 16 + l15) * 32 + lg * 8];
      float ss = 0.f;
#pragma unroll
      for (int j = 0; j < 8; ++j) { float k = bf2f(kf[tj][j]); ss += k * k; }
      ss += __shfl_xor(ss, 16); ss += __shfl_xor(ss, 32);
      float f = 1.f / fmaxf(sqrtf(ss), 1e-6f);
#pragma unroll
      for (int j = 0; j < 8; ++j) kf[tj][j] = f2bf(bf2f(kf[tj][j]) * f);
    }
    f32x4 sacc[4][4];
    __builtin_amdgcn_s_setprio(1);
#pragma unroll
    for (int ti = 0; ti < 4; ++ti)
#pragma unroll
      for (int tj = 0; tj < 4; ++tj) sacc[ti][tj] = MFMA(qf[ti], kf[tj], zf);
    __builtin_amdgcn_s_setprio(0);

    if (SHIFTED) {
      int idc[4];
#pragma unroll
      for (int tj = 0; tj < 4; ++tj) idc[tj] = ids[tj * 16 + l15];
#pragma unroll
      for (int ti = 0; ti < 4; ++ti)
#pragma unroll
        for (int idx = 0; idx < 4; ++idx) {
          int idr = ids[ti * 16 + lg * 4 + idx];
#pragma unroll
          for (int tj = 0; tj < 4; ++tj)
            if (idr != idc[tj]) sacc[ti][tj][idx] += -1e4f;
        }
    }
#pragma unroll
    for (int ti = 0; ti < 4; ++ti) {
#pragma unroll
      for (int idx = 0; idx < 4; ++idx) {
        float m = fmaxf(fmaxf(sacc[ti][0][idx], sacc[ti][1][idx]),
                        fmaxf(sacc[ti][2][idx], sacc[ti][3][idx]));
        m = fmaxf(m, __shfl_xor(m, 1));
        m = fmaxf(m, __shfl_xor(m, 2));
        m = fmaxf(m, __shfl_xor(m, 4));
        m = fmaxf(m, __shfl_xor(m, 8));
        float e0 = __expf(sacc[ti][0][idx] - m);
        float e1 = __expf(sacc[ti][1][idx] - m);
        float e2 = __expf(sacc[ti][2][idx] - m);
        float e3 = __expf(sacc[ti][3][idx] - m);
        float s = e0 + e1 + e2 + e3;
        s += __shfl_xor(s, 1); s += __shfl_xor(s, 2);
        s += __shfl_xor(s, 4); s += __shfl_xor(s, 8);
        float inv = 1.f / s;
        sacc[ti][0][idx] = e0 * inv; sacc[ti][1][idx] = e1 * inv;
        sacc[ti][2][idx] = e2 * inv; sacc[ti][3][idx] = e3 * inv;
      }
    }
#pragma unroll
    for (int ti = 0; ti < 4; ++ti)
#pragma unroll
      for (int tj = 0; tj < 4; ++tj)
#pragma unroll
        for (int idx = 0; idx < 4; ++idx)
          Plds[wid][ti * 16 + lg * 4 + idx][tj * 16 + l15] = f2bf(sacc[ti][tj][idx]);

    f32x4 oacc[4][2];
#pragma unroll
    for (int ti = 0; ti < 4; ++ti)
#pragma unroll
      for (int vj = 0; vj < 2; ++vj) oacc[ti][vj] = zf;
#pragma unroll
    for (int ks = 0; ks < 2; ++ks) {
      bf16x8 pf[4], vf[2];
#pragma unroll
      for (int ti = 0; ti < 4; ++ti) pf[ti] = *(bf16x8*)&Plds[wid][ti * 16 + l15][ks * 32 + lg * 8];
#pragma unroll
      for (int vj = 0; vj < 2; ++vj) vf[vj] = *(const bf16x8*)&Vt[(vj * 16 + l15) * 64 + ks * 32 + lg * 8];
      __builtin_amdgcn_s_setprio(1);
#pragma unroll
      for (int ti = 0; ti < 4; ++ti)
#pragma unroll
        for (int vj = 0; vj < 2; ++vj) oacc[ti][vj] = MFMA(pf[ti], vf[vj], oacc[ti][vj]);
      __builtin_amdgcn_s_setprio(0);
    }
#pragma unroll
    for (int ti = 0; ti < 4; ++ti)
#pragma unroll
      for (int vj = 0; vj < 2; ++vj)
#pragma unroll
        for (int idx = 0; idx < 4; ++idx)
          Olds[ti * 16 + lg * 4 + idx][h * 32 + vj * 16 + l15] = f2bf(oacc[ti][vj][idx]);
  }
  __syncthreads();

  f32x4 pacc[4][4];
#pragma unroll
  for (int i = 0; i < 4; ++i)
#pragma unroll
    for (int j = 0; j < 4; ++j) pacc[i][j] = zf;
#pragma unroll
  for (int kc = 0; kc < 8; ++kc) {
    bf16x8 af[4], bfr[4];
#pragma unroll
    for (int ti = 0; ti < 4; ++ti) af[ti] = *(bf16x8*)&Olds[ti * 16 + l15][kc * 32 + lg * 8];
#pragma unroll
    for (int tj = 0; tj < 4; ++tj)
      bfr[tj] = *(const bf16x8*)&projT[(wid * 64 + tj * 16 + l15) * 256 + kc * 32 + lg * 8];
    __builtin_amdgcn_s_setprio(1);
#pragma unroll
    for (int ti = 0; ti < 4; ++ti)
#pragma unroll
      for (int tj = 0; tj < 4; ++tj) pacc[ti][tj] = MFMA(af[ti], bfr[tj], pacc[ti][tj]);
    __builtin_amdgcn_s_setprio(0);
  }
#pragma unroll
  for (int tj = 0; tj < 4; ++tj) {
    float bv = proj_b[wid * 64 + tj * 16 + l15];
#pragma unroll
    for (int ti = 0; ti < 4; ++ti)
#pragma unroll
      for (int idx = 0; idx < 4; ++idx) pacc[ti][tj][idx] += bv;
  }

#pragma unroll
  for (int ti = 0; ti < 4; ++ti) {
#pragma unroll
    for (int idx = 0; idx < 4; ++idx) {
      float s1 = 0.f, s2 = 0.f;
#pragma unroll
      for (int tj = 0; tj < 4; ++tj) { float v = pacc[ti][tj][idx]; s1 += v; s2 += v * v; }
#pragma unroll
      for (int m = 1; m <= 8; m <<= 1) { s1 += __shfl_xor(s1, m); s2 += __shfl_xor(s2, m); }
      if (l15 == 0) { int row = ti * 16 + lg * 4 + idx; red1[wid][row] = s1; red2[wid][row] = s2; }
    }
  }
  __syncthreads();
#pragma unroll
  for (int ti = 0; ti < 4; ++ti) {
#pragma unroll
    for (int idx = 0; idx < 4; ++idx) {
      int row = ti * 16 + lg * 4 + idx;
      float t1 = red1[0][row] + red1[1][row] + red1[2][row] + red1[3][row];
      float t2 = red2[0][row] + red2[1][row] + red2[2][row] + red2[3][row];
      float mu = t1 * 0.00390625f;
      float var = t2 * 0.00390625f - mu * mu;
      float rstd = rsqrtf(var + 1e-5f);
      int hs = h0 + (row >> 3), ws2 = w0c + (row & 7);
      if (SHIFTED) { hs = (hs + 4) & 63; ws2 = (ws2 + 4) & 63; }
      int tok = b * 4096 + hs * 64 + ws2;
#pragma unroll
      for (int tj = 0; tj < 4; ++tj) {
        int c = wid * 64 + tj * 16 + l15;
        float yn = (pacc[ti][tj][idx] - mu) * rstd * ln_w[c] + ln_b[c];
        float xn = x_old[tok * 256 + c] + yn;
        x_new[tok * 256 + c] = xn;
        x_new_bf[tok * 256 + c] = f2bf(xn);
      }
    }
  }
}

// ---------- MLP GEMM 1: hidden = gelu(x @ W1 + b1) (measured-good, unchanged) ----------
__global__ __launch_bounds__(512) void mlp1_kernel(
    const short* __restrict__ xb,
    const short* __restrict__ w1T, const float* __restrict__ b1,
    short* __restrict__ hidden, int tok_base) {
  __shared__ short A[128 * 64];
  __shared__ short Bs[256 * 64];
  const int mloc = blockIdx.x;
  const int n0 = blockIdx.y * 256;
  const int tid = threadIdx.x;
  const int lane = tid & 63, wid = tid >> 6;
  const int wr = wid >> 2, wc = wid & 3;
  const int l15 = lane & 15, lg = lane >> 4;
  const int lrow = lane >> 3, lcol8 = (lane & 7) * 8;

  f32x4 zf = {0.f, 0.f, 0.f, 0.f};
  f32x4 acc[4][4];
#pragma unroll
  for (int i = 0; i < 4; ++i)
#pragma unroll
    for (int j = 0; j < 4; ++j) acc[i][j] = zf;

  const int tok0 = tok_base + mloc * 128;

#pragma unroll 1
  for (int kc = 0; kc < 4; ++kc) {
    __syncthreads();
#pragma unroll
    for (int it = 0; it < 2; ++it) {
      int r0 = wid * 16 + it * 8;
      GLOAD16(&xb[(size_t)(tok0 + r0 + lrow) * 256 + kc * 64 + lcol8], &A[r0 * 64]);
    }
#pragma unroll
    for (int it = 0; it < 4; ++it) {
      int c0 = wid * 32 + it * 8;
      GLOAD16(&w1T[(size_t)(n0 + c0 + lrow) * 256 + kc * 64 + lcol8], &Bs[c0 * 64]);
    }
    __syncthreads();
#pragma unroll
    for (int ks = 0; ks < 2; ++ks) {
      bf16x8 af[4], bfr[4];
#pragma unroll
      for (int ti = 0; ti < 4; ++ti)
        af[ti] = *(bf16x8*)&A[(wr * 64 + ti * 16 + l15) * 64 + ks * 32 + lg * 8];
#pragma unroll
      for (int tj = 0; tj < 4; ++tj)
        bfr[tj] = *(bf16x8*)&Bs[(wc * 64 + tj * 16 + l15) * 64 + ks * 32 + lg * 8];
#pragma unroll
      for (int ti = 0; ti < 4; ++ti)
#pragma unroll
        for (int tj = 0; tj < 4; ++tj) acc[ti][tj] = MFMA(af[ti], bfr[tj], acc[ti][tj]);
    }
  }
#pragma unroll
  for (int tj = 0; tj < 4; ++tj) {
    int col = n0 + wc * 64 + tj * 16 + l15;
    float bv = b1[col];
#pragma unroll
    for (int ti = 0; ti < 4; ++ti) {
      int rbase = mloc * 128 + wr * 64 + ti * 16 + lg * 4;
#pragma unroll
      for (int idx = 0; idx < 4; ++idx) {
        float v = acc[ti][tj][idx] + bv;
        float g = 0.5f * v * (1.f + erff(v * 0.70710678118654752f));
        hidden[(size_t)(rbase + idx) * 1024 + col] = f2bf(g);
      }
    }
  }
}

// ---------- MLP GEMM 2: x = x + LN(hidden @ W2 + b2) (measured-good, unchanged) ----------
__global__ __launch_bounds__(512) void mlp2_kernel(
    const short* __restrict__ hidden,
    const short* __restrict__ w2T, const float* __restrict__ b2,
    const float* __restrict__ ln_w, const float* __restrict__ ln_b,
    const float* x_old, float* x_new, short* x_new_bf, int tok_base) {
  __shared__ short A[128 * 64];
  __shared__ short Bs[256 * 64];
  __shared__ float red1[128][4], red2[128][4];
  const int mloc = blockIdx.x;
  const int tid = threadIdx.x;
  const int lane = tid & 63, wid = tid >> 6;
  const int wr = wid >> 2, wc = wid & 3;
  const int l15 = lane & 15, lg = lane >> 4;
  const int lrow = lane >> 3, lcol8 = (lane & 7) * 8;

  f32x4 zf = {0.f, 0.f, 0.f, 0.f};
  f32x4 acc[4][4];
#pragma unroll
  for (int i = 0; i < 4; ++i)
#pragma unroll
    for (int j = 0; j < 4; ++j) acc[i][j] = zf;

#pragma unroll 1
  for (int kc = 0; kc < 16; ++kc) {
    __syncthreads();
#pragma unroll
    for (int it = 0; it < 2; ++it) {
      int r0 = wid * 16 + it * 8;
      GLOAD16(&hidden[(size_t)(mloc * 128 + r0 + lrow) * 1024 + kc * 64 + lcol8], &A[r0 * 64]);
    }
#pragma unroll
    for (int it = 0; it < 4; ++it) {
      int c0 = wid * 32 + it * 8;
      GLOAD16(&w2T[(size_t)(c0 + lrow) * 1024 + kc * 64 + lcol8], &Bs[c0 * 64]);
    }
    __syncthreads();
#pragma unroll
    for (int ks = 0; ks < 2; ++ks) {
      bf16x8 af[4], bfr[4];
#pragma unroll
      for (int ti = 0; ti < 4; ++ti)
        af[ti] = *(bf16x8*)&A[(wr * 64 + ti * 16 + l15) * 64 + ks * 32 + lg * 8];
#pragma unroll
      for (int tj = 0; tj < 4; ++tj)
        bfr[tj] = *(bf16x8*)&Bs[(wc * 64 + tj * 16 + l15) * 64 + ks * 32 + lg * 8];
#pragma unroll
      for (int ti = 0; ti < 4; ++ti)
#pragma unroll
        for (int tj = 0; tj < 4; ++tj) acc[ti][tj] = MFMA(af[ti], bfr[tj], acc[ti][tj]);
    }
  }
#pragma unroll
  for (int tj = 0; tj < 4; ++tj) {
    float bv = b2[wc * 64 + tj * 16 + l15];
#pragma unroll
    for (int ti = 0; ti < 4; ++ti)
#pragma unroll
      for (int idx = 0; idx < 4; ++idx) acc[ti][tj][idx] += bv;
  }
#pragma unroll
  for (int ti = 0; ti < 4; ++ti) {
#pragma unroll
    for (int idx = 0; idx < 4; ++idx) {
      float s1 = 0.f, s2 = 0.f;
#pragma unroll
      for (int tj = 0; tj < 4; ++tj) { float v = acc[ti][tj][idx]; s1 += v; s2 += v * v; }
#pragma unroll
      for (int m = 1; m <= 8; m <<= 1) { s1 += __shfl_xor(s1, m); s2 += __shfl_xor(s2, m); }
      if (l15 == 0) {
        int row = wr * 64 + ti * 16 + lg * 4 + idx;
        red1[row][wc] = s1; red2[row][wc] = s2;
      }
    }
  }
  __syncthreads();
#pragma unroll
  for (int ti = 0; ti < 4; ++ti) {
#pragma unroll
    for (int idx = 0; idx < 4; ++idx) {
      int row = wr * 64 + ti * 16 + lg * 4 + idx;
      float t1 = red1[row][0] + red1[row][1] + red1[row][2] + red1[row][3];
      float t2 = red2[row][0] + red2[row][1] + red2[row][2] + red2[row][3];
      float mu = t1 * 0.00390625f;
      float var = t2 * 0.00390625f - mu * mu;
      float rstd = rsqrtf(var + 1e-5f);
      size_t tok = (size_t)tok_base + mloc * 128 + row;
#pragma unroll
      for (int tj = 0; tj < 4; ++tj) {
        int c = wc * 64 + tj * 16 + l15;
        float yn = (acc[ti][tj][idx] - mu) * rstd * ln_w[c] + ln_b[c];
        float xn = x_old[tok * 256 + c] + yn;
        x_new[tok * 256 + c] = xn;
        x_new_bf[tok * 256 + c] = f2bf(xn);
      }
    }
  }
}

// ---------- host ----------
extern "C" void kernel_launch(void* const* d_in, const int* in_sizes, int n_in,
                              void* d_out, int out_size, void* d_ws, size_t ws_size,
                              hipStream_t stream) {
  (void)in_sizes; (void)n_in; (void)out_size;
  const float* x  = (const float*)d_in[0];
  const float* qw[2] = {(const float*)d_in[1], (const float*)d_in[6]};
  const float* qb[2] = {(const float*)d_in[2], (const float*)d_in[7]};
  const float* pw[2] = {(const float*)d_in[3], (const float*)d_in[8]};
  const float* pb[2] = {(const float*)d_in[4], (const float*)d_in[9]};
  const float* ls[2] = {(const float*)d_in[5], (const float*)d_in[10]};
  const float* lnw = (const float*)d_in[11];
  const float* lnb = (const float*)d_in[12];
  const float* w1 = (const float*)d_in[13];
  const float* b1 = (const float*)d_in[14];
  const float* w2 = (const float*)d_in[15];
  const float* b2 = (const float*)d_in[16];
  float* xout = (float*)d_out;

  char* ws = (char*)d_ws;
  short* xb = (short*)ws;  // 33,554,432 B bf16 mirror of current x

  // region unions {Q,K,V} (attn phases) with hidden (MLP phases)
  int nchunk = 1;
  for (; nchunk < 16; nchunk *= 2) {
    size_t need = 33554432ull + (size_t)(1024 / nchunk) * 131072ull + 2097152ull;
    if (need <= ws_size) break;
  }
  int nmb = 1024 / nchunk;        // 64-token window-blocks per chunk
  int nmlp = 512 / nchunk;        // 128-token blocks per chunk
  char* region = ws + 33554432;
  short* Qb = (short*)region;
  short* Kb = (short*)(region + (size_t)nmb * 32768);
  short* Vb = (short*)(region + (size_t)nmb * 65536);
  short* hid = (short*)region;
  char* wbase = region + (size_t)nmb * 131072ull;
  short* qwT[2] = {(short*)wbase, (short*)(wbase + 393216)};
  short* pwT[2] = {(short*)(wbase + 786432), (short*)(wbase + 917504)};
  short* w1T = (short*)(wbase + 1048576);
  short* w2T = (short*)(wbase + 1572864);

  convert_kernel<<<12288, 256, 0, stream>>>(x, qw[0], qw[1], pw[0], pw[1], w1, w2,
                                            xb, qwT[0], qwT[1], pwT[0], pwT[1], w1T, w2T);
  // phase 1: x = x + LN(WMSA(x))
  for (int c = 0; c < nchunk; ++c) {
    qkv_kernel<false><<<dim3(nmb / 2, 3), 512, 0, stream>>>(xb, qwT[0], qb[0], Qb, Kb, Vb, c * nmb);
    attn_kernel<false><<<nmb, 256, 0, stream>>>(Qb, Kb, Vb, ls[0], pwT[0], pb[0], lnw, lnb,
                                                x, xout, xb, c * nmb);
  }
  // phase 2: x = x + LN(MLP(x))
  for (int c = 0; c < nchunk; ++c) {
    mlp1_kernel<<<dim3(nmlp, 4), 512, 0, stream>>>(xb, w1T, b1, hid, c * nmlp * 128);
    mlp2_kernel<<<nmlp, 512, 0, stream>>>(hid, w2T, b2, lnw, lnb, xout, xout, xb, c * nmlp * 128);
  }
  // phase 3: x = x + LN(SWMSA(x))
  for (int c = 0; c < nchunk; ++c) {
    qkv_kernel<true><<<dim3(nmb / 2, 3), 512, 0, stream>>>(xb, qwT[1], qb[1], Qb, Kb, Vb, c * nmb);
    attn_kernel<true><<<nmb, 256, 0, stream>>>(Qb, Kb, Vb, ls[1], pwT[1], pb[1], lnw, lnb,
                                               xout, xout, xb, c * nmb);
  }
  // phase 4: x = x + LN(MLP(x))
  for (int c = 0; c < nchunk; ++c) {
    mlp1_kernel<<<dim3(nmlp, 4), 512, 0, stream>>>(xb, w1T, b1, hid, c * nmlp * 128);
    mlp2_kernel<<<nmlp, 512, 0, stream>>>(hid, w2T, b2, lnw, lnb, xout, xout, xb, c * nmlp * 128);
  }
}

// Round 11
// 857.555 us; speedup vs baseline: 1.2472x; 1.2472x over previous
//
#include <hip/hip_runtime.h>
#include <math.h>

// ---------- types & helpers ----------
typedef __attribute__((ext_vector_type(4))) float f32x4;
typedef __attribute__((ext_vector_type(8))) short bf16x8;

__device__ __forceinline__ short f2bf(float f) {
  unsigned u = __builtin_bit_cast(unsigned, f);
  u += 0x7FFFu + ((u >> 16) & 1u);          // RNE
  return (short)(u >> 16);
}
__device__ __forceinline__ float bf2f(short s) {
  unsigned u = ((unsigned)(unsigned short)s) << 16;
  return __builtin_bit_cast(float, u);
}

#define MFMA(A, B, C) __builtin_amdgcn_mfma_f32_16x16x32_bf16((A), (B), (C), 0, 0, 0)

// async global->LDS, 16B per lane; LDS dst is wave-uniform base + lane*16
#define GLOAD16(gsrc, ldst)                                                      \
  __builtin_amdgcn_global_load_lds(                                              \
      (const __attribute__((address_space(1))) void*)(gsrc),                     \
      (__attribute__((address_space(3))) void*)(ldst), 16, 0, 0)

#define LOG100 4.605170185988092f

// ---------- convert: x -> bf16, weights -> transposed bf16 ----------
__global__ __launch_bounds__(256) void convert_kernel(
    const float* __restrict__ x,
    const float* __restrict__ qw0, const float* __restrict__ qw1,
    const float* __restrict__ pw0, const float* __restrict__ pw1,
    const float* __restrict__ w1, const float* __restrict__ w2,
    short* __restrict__ xb,
    short* __restrict__ qwT0, short* __restrict__ qwT1,
    short* __restrict__ pwT0, short* __restrict__ pwT1,
    short* __restrict__ w1T, short* __restrict__ w2T) {
  int bid = blockIdx.x;
  int tid = threadIdx.x;
  if (bid < 8192) {  // x: 16777216 elements, 8 per thread
    int base = (bid * 256 + tid) * 8;
    bf16x8 o;
#pragma unroll
    for (int j = 0; j < 8; ++j) o[j] = f2bf(x[base + j]);
    *(bf16x8*)&xb[base] = o;
    return;
  }
  int idx = (bid - 8192) * 256 + tid;  // 0..1048575 over weights
  if (idx < 196608) { int n = idx >> 8, k = idx & 255; qwT0[idx] = f2bf(qw0[k * 768 + n]); return; }
  idx -= 196608;
  if (idx < 196608) { int n = idx >> 8, k = idx & 255; qwT1[idx] = f2bf(qw1[k * 768 + n]); return; }
  idx -= 196608;
  if (idx < 65536) { int n = idx >> 8, k = idx & 255; pwT0[idx] = f2bf(pw0[k * 256 + n]); return; }
  idx -= 65536;
  if (idx < 65536) { int n = idx >> 8, k = idx & 255; pwT1[idx] = f2bf(pw1[k * 256 + n]); return; }
  idx -= 65536;
  if (idx < 262144) { int n = idx >> 8, k = idx & 255; w1T[idx] = f2bf(w1[k * 1024 + n]); return; }
  idx -= 262144;
  { int n = idx >> 10, k = idx & 1023; w2T[idx] = f2bf(w2[k * 256 + n]); }
}

// ---------- qkv GEMM: 8-wave BM=128 (2 windows), BN=256, gload_lds staging ----------
template <bool SHIFTED>
__global__ __launch_bounds__(512) void qkv_kernel(
    const short* __restrict__ xb, const short* __restrict__ wT,
    const float* __restrict__ bias,
    short* __restrict__ Q, short* __restrict__ K, short* __restrict__ V,
    int mblk_base) {
  __shared__ short A[128 * 64];   // 16 KB, row r at A[r*64]
  __shared__ short Bs[256 * 64];  // 32 KB, col c at Bs[c*64]
  const int mloc = blockIdx.x;          // window-pair within chunk
  const int which = blockIdx.y;
  const int tid = threadIdx.x;
  const int lane = tid & 63, wid = tid >> 6;
  const int wr = wid >> 2, wc = wid & 3;
  const int l15 = lane & 15, lg = lane >> 4;
  const int lrow = lane >> 3, lcol8 = (lane & 7) * 8;

  // per-lane gathered token for the lane's two staged rows (it=0,1)
  int tokA[2];
#pragma unroll
  for (int it = 0; it < 2; ++it) {
    int r = wid * 16 + it * 8 + lrow;          // block-row 0..127
    int mg = mblk_base + mloc * 2 + (r >> 6);  // global window id
    int b = mg >> 6, wi = mg & 63;
    int hs = ((wi >> 3) << 3) + ((r >> 3) & 7);
    int ws2 = ((wi & 7) << 3) + (r & 7);
    if (SHIFTED) { hs = (hs + 4) & 63; ws2 = (ws2 + 4) & 63; }
    tokA[it] = b * 4096 + hs * 64 + ws2;
  }

  f32x4 zf = {0.f, 0.f, 0.f, 0.f};
  f32x4 acc[4][4];
#pragma unroll
  for (int i = 0; i < 4; ++i)
#pragma unroll
    for (int j = 0; j < 4; ++j) acc[i][j] = zf;

#pragma unroll 1
  for (int kc = 0; kc < 4; ++kc) {
    __syncthreads();
#pragma unroll
    for (int it = 0; it < 2; ++it) {
      int r0 = wid * 16 + it * 8;
      GLOAD16(&xb[(size_t)tokA[it] * 256 + kc * 64 + lcol8], &A[r0 * 64]);
    }
#pragma unroll
    for (int it = 0; it < 4; ++it) {
      int c0 = wid * 32 + it * 8;
      GLOAD16(&wT[(size_t)(which * 256 + c0 + lrow) * 256 + kc * 64 + lcol8], &Bs[c0 * 64]);
    }
    __syncthreads();
#pragma unroll
    for (int ks = 0; ks < 2; ++ks) {
      bf16x8 af[4], bfr[4];
#pragma unroll
      for (int ti = 0; ti < 4; ++ti)
        af[ti] = *(bf16x8*)&A[(wr * 64 + ti * 16 + l15) * 64 + ks * 32 + lg * 8];
#pragma unroll
      for (int tj = 0; tj < 4; ++tj)
        bfr[tj] = *(bf16x8*)&Bs[(wc * 64 + tj * 16 + l15) * 64 + ks * 32 + lg * 8];
#pragma unroll
      for (int ti = 0; ti < 4; ++ti)
#pragma unroll
        for (int tj = 0; tj < 4; ++tj) acc[ti][tj] = MFMA(af[ti], bfr[tj], acc[ti][tj]);
    }
  }
  // epilogue: +bias, write bf16 window layout (V transposed). wave's window = mloc*2+wr.
  short* outp = (which == 0) ? Q : (which == 1) ? K : V;
  const int lw = mloc * 2 + wr;   // chunk-local window
#pragma unroll
  for (int tj = 0; tj < 4; ++tj) {
    int c = wc * 64 + tj * 16 + l15;      // 0..255 within Q|K|V
    int h = c >> 5, d = c & 31;
    float bv = bias[which * 256 + c];
    int hb = (lw * 8 + h) * 2048;
#pragma unroll
    for (int ti = 0; ti < 4; ++ti) {
#pragma unroll
      for (int idx = 0; idx < 4; ++idx) {
        int n = ti * 16 + lg * 4 + idx;   // token within window
        float v = acc[ti][tj][idx] + bv;
        int off = hb + (which == 2 ? (d * 64 + n) : (n * 32 + d));
        outp[off] = f2bf(v);
      }
    }
  }
}

// ---------- fused attention + proj + LN + residual ----------
// Swapped QK^T: compute S^T = mfma(K, Q) so softmax over kv is mostly lane-local
// (2 shfls per query instead of 8 per element). Scatter to Plds transposes back.
template <bool SHIFTED>
__global__ __launch_bounds__(256, 2) void attn_kernel(
    const short* __restrict__ Q, const short* __restrict__ K, const short* __restrict__ V,
    const float* __restrict__ logit_scale,
    const short* __restrict__ projT, const float* __restrict__ proj_b,
    const float* __restrict__ ln_w, const float* __restrict__ ln_b,
    const float* x_old, float* x_new, short* x_new_bf,
    int mblk_base) {
  __shared__ short Plds[4][64][72];
  __shared__ short Olds[64][264];
  __shared__ float red1[4][64], red2[4][64];
  __shared__ int ids[64];

  const int mloc = blockIdx.x;
  const int mg = mblk_base + mloc;
  const int b = mg >> 6, wi = mg & 63;
  const int h0 = (wi >> 3) << 3, w0c = (wi & 7) << 3;
  const int tid = threadIdx.x;
  const int lane = tid & 63, wid = tid >> 6;
  const int l15 = lane & 15, lg = lane >> 4;

  if (SHIFTED) {
    if (tid < 64) {
      int hs = h0 + (tid >> 3), ws2 = w0c + (tid & 7);
      int rr = (hs < 56) ? 0 : ((hs < 60) ? 1 : 2);
      int rc = (ws2 < 56) ? 0 : ((ws2 < 60) ? 1 : 2);
      ids[tid] = rr * 3 + rc;
    }
    __syncthreads();
  }

  f32x4 zf = {0.f, 0.f, 0.f, 0.f};

#pragma unroll
  for (int hp = 0; hp < 2; ++hp) {
    const int h = wid * 2 + hp;
    const short* Qh = Q + (mloc * 8 + h) * 2048;
    const short* Kh = K + (mloc * 8 + h) * 2048;
    const short* Vt = V + (mloc * 8 + h) * 2048;
    const float sc = __expf(fminf(logit_scale[h], LOG100));

    bf16x8 qf[4];
#pragma unroll
    for (int ti = 0; ti < 4; ++ti) {
      qf[ti] = *(const bf16x8*)&Qh[(ti * 16 + l15) * 32 + lg * 8];
      float ss = 0.f;
#pragma unroll
      for (int j = 0; j < 8; ++j) { float q = bf2f(qf[ti][j]); ss += q * q; }
      ss += __shfl_xor(ss, 16); ss += __shfl_xor(ss, 32);
      float f = sc / fmaxf(sqrtf(ss), 1e-6f);
#pragma unroll
      for (int j = 0; j < 8; ++j) qf[ti][j] = f2bf(bf2f(qf[ti][j]) * f);
    }
    bf16x8 kf[4];
#pragma unroll
    for (int tj = 0; tj < 4; ++tj) {
      kf[tj] = *(const bf16x8*)&Kh[(tj * 16 + l15) * 32 + lg * 8];
      float ss = 0.f;
#pragma unroll
      for (int j = 0; j < 8; ++j) { float k = bf2f(kf[tj][j]); ss += k * k; }
      ss += __shfl_xor(ss, 16); ss += __shfl_xor(ss, 32);
      float f = 1.f / fmaxf(sqrtf(ss), 1e-6f);
#pragma unroll
      for (int j = 0; j < 8; ++j) kf[tj][j] = f2bf(bf2f(kf[tj][j]) * f);
    }
    // S^T = K @ Q^T : sacc[ki][qj], per tile row = kv (lg*4+idx), col = q (l15)
    f32x4 sacc[4][4];
    __builtin_amdgcn_s_setprio(1);
#pragma unroll
    for (int ki = 0; ki < 4; ++ki)
#pragma unroll
      for (int qj = 0; qj < 4; ++qj) sacc[ki][qj] = MFMA(kf[ki], qf[qj], zf);
    __builtin_amdgcn_s_setprio(0);

    if (SHIFTED) {
      int idq[4];
#pragma unroll
      for (int qj = 0; qj < 4; ++qj) idq[qj] = ids[qj * 16 + l15];
#pragma unroll
      for (int ki = 0; ki < 4; ++ki)
#pragma unroll
        for (int idx = 0; idx < 4; ++idx) {
          int idr = ids[ki * 16 + lg * 4 + idx];
#pragma unroll
          for (int qj = 0; qj < 4; ++qj)
            if (idr != idq[qj]) sacc[ki][qj][idx] += -1e4f;
        }
    }
    // softmax over kv (rows of S^T) per query column: local 16 + 2 shfls
#pragma unroll
    for (int qj = 0; qj < 4; ++qj) {
      float m = sacc[0][qj][0];
#pragma unroll
      for (int ki = 0; ki < 4; ++ki)
#pragma unroll
        for (int idx = 0; idx < 4; ++idx) m = fmaxf(m, sacc[ki][qj][idx]);
      m = fmaxf(m, __shfl_xor(m, 16));
      m = fmaxf(m, __shfl_xor(m, 32));
      float s = 0.f;
#pragma unroll
      for (int ki = 0; ki < 4; ++ki)
#pragma unroll
        for (int idx = 0; idx < 4; ++idx) {
          float e = __expf(sacc[ki][qj][idx] - m);
          sacc[ki][qj][idx] = e;
          s += e;
        }
      s += __shfl_xor(s, 16);
      s += __shfl_xor(s, 32);
      float inv = 1.f / s;
#pragma unroll
      for (int ki = 0; ki < 4; ++ki)
#pragma unroll
        for (int idx = 0; idx < 4; ++idx) sacc[ki][qj][idx] *= inv;
    }
    // scatter transposed back: Plds[q][kv]
#pragma unroll
    for (int ki = 0; ki < 4; ++ki)
#pragma unroll
      for (int qj = 0; qj < 4; ++qj)
#pragma unroll
        for (int idx = 0; idx < 4; ++idx)
          Plds[wid][qj * 16 + l15][ki * 16 + lg * 4 + idx] = f2bf(sacc[ki][qj][idx]);

    f32x4 oacc[4][2];
#pragma unroll
    for (int ti = 0; ti < 4; ++ti)
#pragma unroll
      for (int vj = 0; vj < 2; ++vj) oacc[ti][vj] = zf;
#pragma unroll
    for (int ks = 0; ks < 2; ++ks) {
      bf16x8 pf[4], vf[2];
#pragma unroll
      for (int ti = 0; ti < 4; ++ti) pf[ti] = *(bf16x8*)&Plds[wid][ti * 16 + l15][ks * 32 + lg * 8];
#pragma unroll
      for (int vj = 0; vj < 2; ++vj) vf[vj] = *(const bf16x8*)&Vt[(vj * 16 + l15) * 64 + ks * 32 + lg * 8];
      __builtin_amdgcn_s_setprio(1);
#pragma unroll
      for (int ti = 0; ti < 4; ++ti)
#pragma unroll
        for (int vj = 0; vj < 2; ++vj) oacc[ti][vj] = MFMA(pf[ti], vf[vj], oacc[ti][vj]);
      __builtin_amdgcn_s_setprio(0);
    }
#pragma unroll
    for (int ti = 0; ti < 4; ++ti)
#pragma unroll
      for (int vj = 0; vj < 2; ++vj)
#pragma unroll
        for (int idx = 0; idx < 4; ++idx)
          Olds[ti * 16 + lg * 4 + idx][h * 32 + vj * 16 + l15] = f2bf(oacc[ti][vj][idx]);
  }
  __syncthreads();

  f32x4 pacc[4][4];
#pragma unroll
  for (int i = 0; i < 4; ++i)
#pragma unroll
    for (int j = 0; j < 4; ++j) pacc[i][j] = zf;
#pragma unroll
  for (int kc = 0; kc < 8; ++kc) {
    bf16x8 af[4], bfr[4];
#pragma unroll
    for (int ti = 0; ti < 4; ++ti) af[ti] = *(bf16x8*)&Olds[ti * 16 + l15][kc * 32 + lg * 8];
#pragma unroll
    for (int tj = 0; tj < 4; ++tj)
      bfr[tj] = *(const bf16x8*)&projT[(wid * 64 + tj * 16 + l15) * 256 + kc * 32 + lg * 8];
    __builtin_amdgcn_s_setprio(1);
#pragma unroll
    for (int ti = 0; ti < 4; ++ti)
#pragma unroll
      for (int tj = 0; tj < 4; ++tj) pacc[ti][tj] = MFMA(af[ti], bfr[tj], pacc[ti][tj]);
    __builtin_amdgcn_s_setprio(0);
  }
#pragma unroll
  for (int tj = 0; tj < 4; ++tj) {
    float bv = proj_b[wid * 64 + tj * 16 + l15];
#pragma unroll
    for (int ti = 0; ti < 4; ++ti)
#pragma unroll
      for (int idx = 0; idx < 4; ++idx) pacc[ti][tj][idx] += bv;
  }

#pragma unroll
  for (int ti = 0; ti < 4; ++ti) {
#pragma unroll
    for (int idx = 0; idx < 4; ++idx) {
      float s1 = 0.f, s2 = 0.f;
#pragma unroll
      for (int tj = 0; tj < 4; ++tj) { float v = pacc[ti][tj][idx]; s1 += v; s2 += v * v; }
#pragma unroll
      for (int m = 1; m <= 8; m <<= 1) { s1 += __shfl_xor(s1, m); s2 += __shfl_xor(s2, m); }
      if (l15 == 0) { int row = ti * 16 + lg * 4 + idx; red1[wid][row] = s1; red2[wid][row] = s2; }
    }
  }
  __syncthreads();
#pragma unroll
  for (int ti = 0; ti < 4; ++ti) {
#pragma unroll
    for (int idx = 0; idx < 4; ++idx) {
      int row = ti * 16 + lg * 4 + idx;
      float t1 = red1[0][row] + red1[1][row] + red1[2][row] + red1[3][row];
      float t2 = red2[0][row] + red2[1][row] + red2[2][row] + red2[3][row];
      float mu = t1 * 0.00390625f;
      float var = t2 * 0.00390625f - mu * mu;
      float rstd = rsqrtf(var + 1e-5f);
      int hs = h0 + (row >> 3), ws2 = w0c + (row & 7);
      if (SHIFTED) { hs = (hs + 4) & 63; ws2 = (ws2 + 4) & 63; }
      int tok = b * 4096 + hs * 64 + ws2;
#pragma unroll
      for (int tj = 0; tj < 4; ++tj) {
        int c = wid * 64 + tj * 16 + l15;
        float yn = (pacc[ti][tj][idx] - mu) * rstd * ln_w[c] + ln_b[c];
        float xn = x_old[tok * 256 + c] + yn;
        x_new[tok * 256 + c] = xn;
        x_new_bf[tok * 256 + c] = f2bf(xn);
      }
    }
  }
}

// ---------- MLP GEMM 1: hidden = gelu(x @ W1 + b1) (measured-good, unchanged) ----------
__global__ __launch_bounds__(512) void mlp1_kernel(
    const short* __restrict__ xb,
    const short* __restrict__ w1T, const float* __restrict__ b1,
    short* __restrict__ hidden, int tok_base) {
  __shared__ short A[128 * 64];
  __shared__ short Bs[256 * 64];
  const int mloc = blockIdx.x;
  const int n0 = blockIdx.y * 256;
  const int tid = threadIdx.x;
  const int lane = tid & 63, wid = tid >> 6;
  const int wr = wid >> 2, wc = wid & 3;
  const int l15 = lane & 15, lg = lane >> 4;
  const int lrow = lane >> 3, lcol8 = (lane & 7) * 8;

  f32x4 zf = {0.f, 0.f, 0.f, 0.f};
  f32x4 acc[4][4];
#pragma unroll
  for (int i = 0; i < 4; ++i)
#pragma unroll
    for (int j = 0; j < 4; ++j) acc[i][j] = zf;

  const int tok0 = tok_base + mloc * 128;

#pragma unroll 1
  for (int kc = 0; kc < 4; ++kc) {
    __syncthreads();
#pragma unroll
    for (int it = 0; it < 2; ++it) {
      int r0 = wid * 16 + it * 8;
      GLOAD16(&xb[(size_t)(tok0 + r0 + lrow) * 256 + kc * 64 + lcol8], &A[r0 * 64]);
    }
#pragma unroll
    for (int it = 0; it < 4; ++it) {
      int c0 = wid * 32 + it * 8;
      GLOAD16(&w1T[(size_t)(n0 + c0 + lrow) * 256 + kc * 64 + lcol8], &Bs[c0 * 64]);
    }
    __syncthreads();
#pragma unroll
    for (int ks = 0; ks < 2; ++ks) {
      bf16x8 af[4], bfr[4];
#pragma unroll
      for (int ti = 0; ti < 4; ++ti)
        af[ti] = *(bf16x8*)&A[(wr * 64 + ti * 16 + l15) * 64 + ks * 32 + lg * 8];
#pragma unroll
      for (int tj = 0; tj < 4; ++tj)
        bfr[tj] = *(bf16x8*)&Bs[(wc * 64 + tj * 16 + l15) * 64 + ks * 32 + lg * 8];
#pragma unroll
      for (int ti = 0; ti < 4; ++ti)
#pragma unroll
        for (int tj = 0; tj < 4; ++tj) acc[ti][tj] = MFMA(af[ti], bfr[tj], acc[ti][tj]);
    }
  }
#pragma unroll
  for (int tj = 0; tj < 4; ++tj) {
    int col = n0 + wc * 64 + tj * 16 + l15;
    float bv = b1[col];
#pragma unroll
    for (int ti = 0; ti < 4; ++ti) {
      int rbase = mloc * 128 + wr * 64 + ti * 16 + lg * 4;
#pragma unroll
      for (int idx = 0; idx < 4; ++idx) {
        float v = acc[ti][tj][idx] + bv;
        float g = 0.5f * v * (1.f + erff(v * 0.70710678118654752f));
        hidden[(size_t)(rbase + idx) * 1024 + col] = f2bf(g);
      }
    }
  }
}

// ---------- MLP GEMM 2: x = x + LN(hidden @ W2 + b2) (measured-good, unchanged) ----------
__global__ __launch_bounds__(512) void mlp2_kernel(
    const short* __restrict__ hidden,
    const short* __restrict__ w2T, const float* __restrict__ b2,
    const float* __restrict__ ln_w, const float* __restrict__ ln_b,
    const float* x_old, float* x_new, short* x_new_bf, int tok_base) {
  __shared__ short A[128 * 64];
  __shared__ short Bs[256 * 64];
  __shared__ float red1[128][4], red2[128][4];
  const int mloc = blockIdx.x;
  const int tid = threadIdx.x;
  const int lane = tid & 63, wid = tid >> 6;
  const int wr = wid >> 2, wc = wid & 3;
  const int l15 = lane & 15, lg = lane >> 4;
  const int lrow = lane >> 3, lcol8 = (lane & 7) * 8;

  f32x4 zf = {0.f, 0.f, 0.f, 0.f};
  f32x4 acc[4][4];
#pragma unroll
  for (int i = 0; i < 4; ++i)
#pragma unroll
    for (int j = 0; j < 4; ++j) acc[i][j] = zf;

#pragma unroll 1
  for (int kc = 0; kc < 16; ++kc) {
    __syncthreads();
#pragma unroll
    for (int it = 0; it < 2; ++it) {
      int r0 = wid * 16 + it * 8;
      GLOAD16(&hidden[(size_t)(mloc * 128 + r0 + lrow) * 1024 + kc * 64 + lcol8], &A[r0 * 64]);
    }
#pragma unroll
    for (int it = 0; it < 4; ++it) {
      int c0 = wid * 32 + it * 8;
      GLOAD16(&w2T[(size_t)(c0 + lrow) * 1024 + kc * 64 + lcol8], &Bs[c0 * 64]);
    }
    __syncthreads();
#pragma unroll
    for (int ks = 0; ks < 2; ++ks) {
      bf16x8 af[4], bfr[4];
#pragma unroll
      for (int ti = 0; ti < 4; ++ti)
        af[ti] = *(bf16x8*)&A[(wr * 64 + ti * 16 + l15) * 64 + ks * 32 + lg * 8];
#pragma unroll
      for (int tj = 0; tj < 4; ++tj)
        bfr[tj] = *(bf16x8*)&Bs[(wc * 64 + tj * 16 + l15) * 64 + ks * 32 + lg * 8];
#pragma unroll
      for (int ti = 0; ti < 4; ++ti)
#pragma unroll
        for (int tj = 0; tj < 4; ++tj) acc[ti][tj] = MFMA(af[ti], bfr[tj], acc[ti][tj]);
    }
  }
#pragma unroll
  for (int tj = 0; tj < 4; ++tj) {
    float bv = b2[wc * 64 + tj * 16 + l15];
#pragma unroll
    for (int ti = 0; ti < 4; ++ti)
#pragma unroll
      for (int idx = 0; idx < 4; ++idx) acc[ti][tj][idx] += bv;
  }
#pragma unroll
  for (int ti = 0; ti < 4; ++ti) {
#pragma unroll
    for (int idx = 0; idx < 4; ++idx) {
      float s1 = 0.f, s2 = 0.f;
#pragma unroll
      for (int tj = 0; tj < 4; ++tj) { float v = acc[ti][tj][idx]; s1 += v; s2 += v * v; }
#pragma unroll
      for (int m = 1; m <= 8; m <<= 1) { s1 += __shfl_xor(s1, m); s2 += __shfl_xor(s2, m); }
      if (l15 == 0) {
        int row = wr * 64 + ti * 16 + lg * 4 + idx;
        red1[row][wc] = s1; red2[row][wc] = s2;
      }
    }
  }
  __syncthreads();
#pragma unroll
  for (int ti = 0; ti < 4; ++ti) {
#pragma unroll
    for (int idx = 0; idx < 4; ++idx) {
      int row = wr * 64 + ti * 16 + lg * 4 + idx;
      float t1 = red1[row][0] + red1[row][1] + red1[row][2] + red1[row][3];
      float t2 = red2[row][0] + red2[row][1] + red2[row][2] + red2[row][3];
      float mu = t1 * 0.00390625f;
      float var = t2 * 0.00390625f - mu * mu;
      float rstd = rsqrtf(var + 1e-5f);
      size_t tok = (size_t)tok_base + mloc * 128 + row;
#pragma unroll
      for (int tj = 0; tj < 4; ++tj) {
        int c = wc * 64 + tj * 16 + l15;
        float yn = (acc[ti][tj][idx] - mu) * rstd * ln_w[c] + ln_b[c];
        float xn = x_old[tok * 256 + c] + yn;
        x_new[tok * 256 + c] = xn;
        x_new_bf[tok * 256 + c] = f2bf(xn);
      }
    }
  }
}

// ---------- host ----------
extern "C" void kernel_launch(void* const* d_in, const int* in_sizes, int n_in,
                              void* d_out, int out_size, void* d_ws, size_t ws_size,
                              hipStream_t stream) {
  (void)in_sizes; (void)n_in; (void)out_size;
  const float* x  = (const float*)d_in[0];
  const float* qw[2] = {(const float*)d_in[1], (const float*)d_in[6]};
  const float* qb[2] = {(const float*)d_in[2], (const float*)d_in[7]};
  const float* pw[2] = {(const float*)d_in[3], (const float*)d_in[8]};
  const float* pb[2] = {(const float*)d_in[4], (const float*)d_in[9]};
  const float* ls[2] = {(const float*)d_in[5], (const float*)d_in[10]};
  const float* lnw = (const float*)d_in[11];
  const float* lnb = (const float*)d_in[12];
  const float* w1 = (const float*)d_in[13];
  const float* b1 = (const float*)d_in[14];
  const float* w2 = (const float*)d_in[15];
  const float* b2 = (const float*)d_in[16];
  float* xout = (float*)d_out;

  char* ws = (char*)d_ws;
  short* xb = (short*)ws;  // 33,554,432 B bf16 mirror of current x

  // region unions {Q,K,V} (attn phases) with hidden (MLP phases)
  int nchunk = 1;
  for (; nchunk < 16; nchunk *= 2) {
    size_t need = 33554432ull + (size_t)(1024 / nchunk) * 131072ull + 2097152ull;
    if (need <= ws_size) break;
  }
  int nmb = 1024 / nchunk;        // 64-token window-blocks per chunk
  int nmlp = 512 / nchunk;        // 128-token blocks per chunk
  char* region = ws + 33554432;
  short* Qb = (short*)region;
  short* Kb = (short*)(region + (size_t)nmb * 32768);
  short* Vb = (short*)(region + (size_t)nmb * 65536);
  short* hid = (short*)region;
  char* wbase = region + (size_t)nmb * 131072ull;
  short* qwT[2] = {(short*)wbase, (short*)(wbase + 393216)};
  short* pwT[2] = {(short*)(wbase + 786432), (short*)(wbase + 917504)};
  short* w1T = (short*)(wbase + 1048576);
  short* w2T = (short*)(wbase + 1572864);

  convert_kernel<<<12288, 256, 0, stream>>>(x, qw[0], qw[1], pw[0], pw[1], w1, w2,
                                            xb, qwT[0], qwT[1], pwT[0], pwT[1], w1T, w2T);
  // phase 1: x = x + LN(WMSA(x))
  for (int c = 0; c < nchunk; ++c) {
    qkv_kernel<false><<<dim3(nmb / 2, 3), 512, 0, stream>>>(xb, qwT[0], qb[0], Qb, Kb, Vb, c * nmb);
    attn_kernel<false><<<nmb, 256, 0, stream>>>(Qb, Kb, Vb, ls[0], pwT[0], pb[0], lnw, lnb,
                                                x, xout, xb, c * nmb);
  }
  // phase 2: x = x + LN(MLP(x))
  for (int c = 0; c < nchunk; ++c) {
    mlp1_kernel<<<dim3(nmlp, 4), 512, 0, stream>>>(xb, w1T, b1, hid, c * nmlp * 128);
    mlp2_kernel<<<nmlp, 512, 0, stream>>>(hid, w2T, b2, lnw, lnb, xout, xout, xb, c * nmlp * 128);
  }
  // phase 3: x = x + LN(SWMSA(x))
  for (int c = 0; c < nchunk; ++c) {
    qkv_kernel<true><<<dim3(nmb / 2, 3), 512, 0, stream>>>(xb, qwT[1], qb[1], Qb, Kb, Vb, c * nmb);
    attn_kernel<true><<<nmb, 256, 0, stream>>>(Qb, Kb, Vb, ls[1], pwT[1], pb[1], lnw, lnb,
                                               xout, xout, xb, c * nmb);
  }
  // phase 4: x = x + LN(MLP(x))
  for (int c = 0; c < nchunk; ++c) {
    mlp1_kernel<<<dim3(nmlp, 4), 512, 0, stream>>>(xb, w1T, b1, hid, c * nmlp * 128);
    mlp2_kernel<<<nmlp, 512, 0, stream>>>(hid, w2T, b2, lnw, lnb, xout, xout, xb, c * nmlp * 128);
  }
}